// Round 4
// baseline (425.986 us; speedup 1.0000x reference)
//
#include <hip/hip_runtime.h>
#include <hip/hip_bf16.h>
#include <math.h>

#define NN 50000
#define NFEAT 256
#define NHID 64
#define NCLASS 40
#define EDGES 800000
#define SCAN_BLK 512

#define W_BKT 32
#define K_BKT ((NN + W_BKT - 1) / W_BKT)      // 1563 buckets of 32 nodes
#define CHUNK 1600
#define NCHUNK ((EDGES + CHUNK - 1) / CHUNK)  // 500 chunks

// ---------------- GEMM1: xw = x @ W1  (f32 tiled, 64x64 tile, 4x4 microtile) ----
#define BM 64
#define BK 32
__global__ __launch_bounds__(256) void k_gemm1(const float* __restrict__ x,
                                               const float* __restrict__ W1,
                                               float* __restrict__ xw) {
    __shared__ float xs[BK][BM + 4];
    __shared__ float ws[BK][NHID];
    const int tid = threadIdx.x;
    const int tx  = tid & 15;
    const int ty  = tid >> 4;
    const int r0  = blockIdx.x * BM;

    float acc[4][4] = {};

    for (int kc = 0; kc < NFEAT; kc += BK) {
        #pragma unroll
        for (int p = 0; p < 2; ++p) {
            int e   = tid * 4 + p * 1024;
            int row = e >> 5;
            int k   = e & 31;
            int gr  = r0 + row;
            float4 v = make_float4(0.f, 0.f, 0.f, 0.f);
            if (gr < NN) v = *(const float4*)&x[(size_t)gr * NFEAT + kc + k];
            xs[k + 0][row] = v.x; xs[k + 1][row] = v.y;
            xs[k + 2][row] = v.z; xs[k + 3][row] = v.w;
        }
        #pragma unroll
        for (int p = 0; p < 2; ++p) {
            int e  = tid * 4 + p * 1024;
            int kk = e >> 6;
            int c  = e & 63;
            *(float4*)&ws[kk][c] = *(const float4*)&W1[(size_t)(kc + kk) * NHID + c];
        }
        __syncthreads();
        #pragma unroll
        for (int kk = 0; kk < BK; ++kk) {
            float4 a = *(const float4*)&xs[kk][ty * 4];
            float4 b = *(const float4*)&ws[kk][tx * 4];
            acc[0][0] += a.x * b.x; acc[0][1] += a.x * b.y; acc[0][2] += a.x * b.z; acc[0][3] += a.x * b.w;
            acc[1][0] += a.y * b.x; acc[1][1] += a.y * b.y; acc[1][2] += a.y * b.z; acc[1][3] += a.y * b.w;
            acc[2][0] += a.z * b.x; acc[2][1] += a.z * b.y; acc[2][2] += a.z * b.z; acc[2][3] += a.z * b.w;
            acc[3][0] += a.w * b.x; acc[3][1] += a.w * b.y; acc[3][2] += a.w * b.z; acc[3][3] += a.w * b.w;
        }
        __syncthreads();
    }
    #pragma unroll
    for (int i = 0; i < 4; ++i) {
        int gr = r0 + ty * 4 + i;
        if (gr < NN)
            *(float4*)&xw[(size_t)gr * NHID + tx * 4] =
                make_float4(acc[i][0], acc[i][1], acc[i][2], acc[i][3]);
    }
}

// ---------------- CSR build ------------------------------------------------
__global__ void k_zero(int* __restrict__ count) {
    int i = blockIdx.x * 256 + threadIdx.x;
    if (i < NN) count[i] = 0;
}

__global__ void k_hist(const int* __restrict__ dst, int* __restrict__ count) {
    int t = blockIdx.x * 256 + threadIdx.x;
    if (t < EDGES / 4) {
        int4 d = ((const int4*)dst)[t];
        atomicAdd(&count[d.x], 1);
        atomicAdd(&count[d.y], 1);
        atomicAdd(&count[d.z], 1);
        atomicAdd(&count[d.w], 1);
    }
}

__global__ __launch_bounds__(SCAN_BLK) void k_scanA(const int* __restrict__ count,
                                                    int* __restrict__ tmp,
                                                    int* __restrict__ blocksum) {
    __shared__ int s[SCAN_BLK];
    int i = blockIdx.x * SCAN_BLK + threadIdx.x;
    int v = (i < NN) ? count[i] : 0;
    s[threadIdx.x] = v;
    __syncthreads();
    for (int off = 1; off < SCAN_BLK; off <<= 1) {
        int t = (threadIdx.x >= off) ? s[threadIdx.x - off] : 0;
        __syncthreads();
        s[threadIdx.x] += t;
        __syncthreads();
    }
    if (i < NN) tmp[i] = s[threadIdx.x];
    if (threadIdx.x == SCAN_BLK - 1) blocksum[blockIdx.x] = s[SCAN_BLK - 1];
}

__global__ void k_scanB(const int* __restrict__ blocksum, int* __restrict__ blockoff, int nb) {
    __shared__ int s[128];
    int v = (threadIdx.x < nb) ? blocksum[threadIdx.x] : 0;
    s[threadIdx.x] = v;
    __syncthreads();
    for (int off = 1; off < 128; off <<= 1) {
        int t = (threadIdx.x >= off) ? s[threadIdx.x - off] : 0;
        __syncthreads();
        s[threadIdx.x] += t;
        __syncthreads();
    }
    if (threadIdx.x < nb) blockoff[threadIdx.x] = s[threadIdx.x] - v;  // exclusive
}

// row_ptr + bucket cursors (bucket start = exclusive prefix at node b*32)
__global__ void k_scanC(const int* __restrict__ tmp, const int* __restrict__ blockoff,
                        const int* __restrict__ count,
                        int* __restrict__ row_ptr, int* __restrict__ bcur) {
    int i = blockIdx.x * 256 + threadIdx.x;
    if (i < NN) {
        int incl = tmp[i] + blockoff[i / SCAN_BLK];
        row_ptr[i + 1] = incl;
        if (i == 0) row_ptr[0] = 0;
        if ((i & (W_BKT - 1)) == 0) bcur[i / W_BKT] = incl - count[i];
    }
}

// ---- Pass 1: bin edges into bucket-major staging. Buckets partitioned by
// bid&7 so each bucket's lines are written from (heuristically) one XCD.
__global__ __launch_bounds__(256) void k_scat1(const int* __restrict__ src,
                                               const int* __restrict__ dst,
                                               const float* __restrict__ val,
                                               int* __restrict__ bcur,
                                               int2* __restrict__ staging) {
    const int res   = blockIdx.x & 7;
    const int base  = (blockIdx.x >> 3) * CHUNK;
    const int end   = min(base + CHUNK, EDGES);
    for (int e = base + threadIdx.x; e < end; e += 256) {
        int d = dst[e];
        int b = d >> 5;
        if ((b & 7) == res) {
            int p = atomicAdd(&bcur[b], 1);
            int2 cv;
            cv.x = src[e] | ((d & (W_BKT - 1)) << 17);   // src < 2^17
            cv.y = __float_as_int(val[e]);
            staging[p] = cv;
        }
    }
}

// ---- Pass 2: within-bucket exact placement via LDS cursors; writes stay in
// the block's own ~4KB region -> full-line merging.
__global__ __launch_bounds__(256) void k_scat2(const int* __restrict__ row_ptr,
                                               const int2* __restrict__ staging,
                                               int2* __restrict__ csr) {
    __shared__ int cur[W_BKT];
    const int nb = blockIdx.x * W_BKT;
    if (threadIdx.x < W_BKT) {
        int node = nb + threadIdx.x;
        cur[threadIdx.x] = (node < NN) ? row_ptr[node] : 0;
    }
    __syncthreads();
    const int beg = row_ptr[nb];
    const int end = row_ptr[min(nb + W_BKT, NN)];
    for (int i = beg + threadIdx.x; i < end; i += 256) {
        int2 cv = staging[i];
        int dl = cv.x >> 17;
        int p  = atomicAdd(&cur[dl], 1);
        csr[p] = make_int2(cv.x & 0x1FFFF, cv.y);
    }
}

// ---------------- SPMM: out[r,:] = sum_j val_j * in[col_j,:]  (d=64) --------
template <bool RELU>
__global__ __launch_bounds__(256) void k_spmm(const float* __restrict__ in,
                                              const int* __restrict__ row_ptr,
                                              const int2* __restrict__ csr,
                                              const float* __restrict__ bias,
                                              float* __restrict__ out) {
    const int lane = threadIdx.x & 63;
    int gw = (blockIdx.x * 256 + threadIdx.x) >> 6;
    if (gw >= NN) return;
    const int r   = __builtin_amdgcn_readfirstlane(gw);
    const int beg = row_ptr[r];
    const int end = row_ptr[r + 1];

    float acc0 = 0.f, acc1 = 0.f;
    int j = beg;
    for (; j + 3 < end; j += 4) {
        int2 a = csr[j], b = csr[j + 1], c = csr[j + 2], d = csr[j + 3];
        acc0 += __int_as_float(a.y) * in[(size_t)a.x * NHID + lane];
        acc1 += __int_as_float(b.y) * in[(size_t)b.x * NHID + lane];
        acc0 += __int_as_float(c.y) * in[(size_t)c.x * NHID + lane];
        acc1 += __int_as_float(d.y) * in[(size_t)d.x * NHID + lane];
    }
    for (; j < end; ++j) {
        int2 a = csr[j];
        acc0 += __int_as_float(a.y) * in[(size_t)a.x * NHID + lane];
    }
    float acc = acc0 + acc1;

    if (RELU)
        out[(size_t)r * NHID + lane] = fmaxf(acc + bias[lane], 0.f);
    else
        out[(size_t)r * NHID + lane] = acc;
}

// ---------------- Fused epilogue: heads + reparam + log_softmax -------------
__global__ __launch_bounds__(256) void k_final(const float* __restrict__ g2,
                                               const float* __restrict__ W11,
                                               const float* __restrict__ b11,
                                               const float* __restrict__ W12,
                                               const float* __restrict__ b12,
                                               const float* __restrict__ eps,
                                               float* __restrict__ out) {
    __shared__ float W11l[NHID * NCLASS];
    __shared__ float W12l[NHID * NCLASS];
    __shared__ float bl[2 * NCLASS];
    for (int i = threadIdx.x; i < NHID * NCLASS; i += 256) {
        W11l[i] = W11[i];
        W12l[i] = W12[i];
    }
    if (threadIdx.x < NCLASS) bl[threadIdx.x] = b11[threadIdx.x];
    else if (threadIdx.x < 2 * NCLASS) bl[threadIdx.x] = b12[threadIdx.x - NCLASS];
    __syncthreads();

    const int lane = threadIdx.x & 63;
    const int gw   = (blockIdx.x * 256 + threadIdx.x) >> 6;
    const bool act = lane < NCLASS;
    const int  cc  = act ? lane : NCLASS - 1;

    const int r0 = gw * 4;
    if (r0 >= NN) return;
    const int ur = __builtin_amdgcn_readfirstlane(r0);
    const float* __restrict__ g = g2 + (size_t)ur * NHID;

    float m[4], lg[4];
    #pragma unroll
    for (int i = 0; i < 4; ++i) { m[i] = bl[cc]; lg[i] = bl[NCLASS + cc]; }

    #pragma unroll 4
    for (int k = 0; k < NHID; ++k) {
        float w1 = W11l[k * NCLASS + cc];
        float w2 = W12l[k * NCLASS + cc];
        float ga = g[k], gb = g[NHID + k], gc = g[2 * NHID + k], gd = g[3 * NHID + k];
        m[0] += ga * w1; lg[0] += ga * w2;
        m[1] += gb * w1; lg[1] += gb * w2;
        m[2] += gc * w1; lg[2] += gc * w2;
        m[3] += gd * w1; lg[3] += gd * w2;
    }

    float z[4];
    #pragma unroll
    for (int i = 0; i < 4; ++i)
        z[i] = act ? (eps[(size_t)(ur + i) * NCLASS + lane] * expf(lg[i]) + m[i]) : -1e30f;

    float zmax[4], s[4];
    #pragma unroll
    for (int i = 0; i < 4; ++i) zmax[i] = z[i];
    #pragma unroll
    for (int off = 32; off >= 1; off >>= 1) {
        #pragma unroll
        for (int i = 0; i < 4; ++i) zmax[i] = fmaxf(zmax[i], __shfl_xor(zmax[i], off));
    }
    #pragma unroll
    for (int i = 0; i < 4; ++i) s[i] = act ? expf(z[i] - zmax[i]) : 0.f;
    #pragma unroll
    for (int off = 32; off >= 1; off >>= 1) {
        #pragma unroll
        for (int i = 0; i < 4; ++i) s[i] += __shfl_xor(s[i], off);
    }
    if (act) {
        #pragma unroll
        for (int i = 0; i < 4; ++i)
            out[(size_t)(ur + i) * NCLASS + lane] = z[i] - zmax[i] - logf(s[i]);
    }
}

// ---------------- launcher --------------------------------------------------
extern "C" void kernel_launch(void* const* d_in, const int* in_sizes, int n_in,
                              void* d_out, int out_size, void* d_ws, size_t ws_size,
                              hipStream_t stream) {
    const float* x        = (const float*)d_in[0];
    const int*   edge_src = (const int*)d_in[1];
    const int*   edge_dst = (const int*)d_in[2];
    const float* edge_val = (const float*)d_in[3];
    const float* eps      = (const float*)d_in[4];
    const float* W1       = (const float*)d_in[5];
    const float* b1       = (const float*)d_in[6];
    const float* W11      = (const float*)d_in[7];
    const float* b11      = (const float*)d_in[8];
    const float* W12      = (const float*)d_in[9];
    const float* b12      = (const float*)d_in[10];
    float* out = (float*)d_out;

    // ws layout; staging aliases h (h first written in spmm1, after scat2)
    int2*  csr     = (int2*)d_ws;                  // EDGES * 8B
    float* xw      = (float*)(csr + EDGES);        // NN*64
    float* h       = xw + (size_t)NN * NHID;       // NN*64
    int2*  staging = (int2*)h;                     // EDGES * 8B (alias)
    int*   count   = (int*)(h + (size_t)NN * NHID);
    int*   tmp     = count + NN;
    int*   row_ptr = tmp + NN;                     // NN+1
    int*   bcur    = row_ptr + (NN + 1);           // K_BKT
    int*   blocksum= bcur + K_BKT;
    int*   blockoff= blocksum + 128;
    float* g2 = xw;                                // xw dead after spmm1

    const int NB = (NN + SCAN_BLK - 1) / SCAN_BLK; // 98

    k_gemm1<<<(NN + BM - 1) / BM, 256, 0, stream>>>(x, W1, xw);
    k_zero<<<(NN + 255) / 256, 256, 0, stream>>>(count);
    k_hist<<<(EDGES / 4 + 255) / 256, 256, 0, stream>>>(edge_dst, count);
    k_scanA<<<NB, SCAN_BLK, 0, stream>>>(count, tmp, blocksum);
    k_scanB<<<1, 128, 0, stream>>>(blocksum, blockoff, NB);
    k_scanC<<<(NN + 255) / 256, 256, 0, stream>>>(tmp, blockoff, count, row_ptr, bcur);
    k_scat1<<<NCHUNK * 8, 256, 0, stream>>>(edge_src, edge_dst, edge_val, bcur, staging);
    k_scat2<<<K_BKT, 256, 0, stream>>>(row_ptr, staging, csr);
    k_spmm<true><<<NN / 4, 256, 0, stream>>>(xw, row_ptr, csr, b1, h);
    k_spmm<false><<<NN / 4, 256, 0, stream>>>(h, row_ptr, csr, nullptr, g2);
    k_final<<<(NN / 4 + 3) / 4, 256, 0, stream>>>(g2, W11, b11, W12, b12, eps, out);
}

// Round 5
// 297.863 us; speedup vs baseline: 1.4301x; 1.4301x over previous
//
#include <hip/hip_runtime.h>
#include <hip/hip_bf16.h>
#include <math.h>

#define NN 50000
#define NFEAT 256
#define NHID 64
#define NCLASS 40
#define EDGES 800000
#define SCAN_BLK 512

// coarse buckets for the two-pass scatter: 512 nodes per bucket
#define BKT_SH 9
#define BKT_W (1 << BKT_SH)                 // 512
#define NBKT ((NN + BKT_W - 1) / BKT_W)     // 98
#define CAP 64                              // LDS bin capacity (λ≈42)
#define NBLK1 196
#define CHUNK1 ((EDGES + NBLK1 - 1) / NBLK1)  // 4082

// ---------------- GEMM1: xw = x @ W1  (f32 tiled, 64x64 tile, 4x4 microtile) ----
#define BM 64
#define BK 32
__global__ __launch_bounds__(256) void k_gemm1(const float* __restrict__ x,
                                               const float* __restrict__ W1,
                                               float* __restrict__ xw) {
    __shared__ float xs[BK][BM + 4];
    __shared__ float ws[BK][NHID];
    const int tid = threadIdx.x;
    const int tx  = tid & 15;
    const int ty  = tid >> 4;
    const int r0  = blockIdx.x * BM;

    float acc[4][4] = {};

    for (int kc = 0; kc < NFEAT; kc += BK) {
        #pragma unroll
        for (int p = 0; p < 2; ++p) {
            int e   = tid * 4 + p * 1024;
            int row = e >> 5;
            int k   = e & 31;
            int gr  = r0 + row;
            float4 v = make_float4(0.f, 0.f, 0.f, 0.f);
            if (gr < NN) v = *(const float4*)&x[(size_t)gr * NFEAT + kc + k];
            xs[k + 0][row] = v.x; xs[k + 1][row] = v.y;
            xs[k + 2][row] = v.z; xs[k + 3][row] = v.w;
        }
        #pragma unroll
        for (int p = 0; p < 2; ++p) {
            int e  = tid * 4 + p * 1024;
            int kk = e >> 6;
            int c  = e & 63;
            *(float4*)&ws[kk][c] = *(const float4*)&W1[(size_t)(kc + kk) * NHID + c];
        }
        __syncthreads();
        #pragma unroll
        for (int kk = 0; kk < BK; ++kk) {
            float4 a = *(const float4*)&xs[kk][ty * 4];
            float4 b = *(const float4*)&ws[kk][tx * 4];
            acc[0][0] += a.x * b.x; acc[0][1] += a.x * b.y; acc[0][2] += a.x * b.z; acc[0][3] += a.x * b.w;
            acc[1][0] += a.y * b.x; acc[1][1] += a.y * b.y; acc[1][2] += a.y * b.z; acc[1][3] += a.y * b.w;
            acc[2][0] += a.z * b.x; acc[2][1] += a.z * b.y; acc[2][2] += a.z * b.z; acc[2][3] += a.z * b.w;
            acc[3][0] += a.w * b.x; acc[3][1] += a.w * b.y; acc[3][2] += a.w * b.z; acc[3][3] += a.w * b.w;
        }
        __syncthreads();
    }
    #pragma unroll
    for (int i = 0; i < 4; ++i) {
        int gr = r0 + ty * 4 + i;
        if (gr < NN)
            *(float4*)&xw[(size_t)gr * NHID + tx * 4] =
                make_float4(acc[i][0], acc[i][1], acc[i][2], acc[i][3]);
    }
}

// ---------------- CSR build ------------------------------------------------
__global__ void k_zero(int* __restrict__ count) {
    int i = blockIdx.x * 256 + threadIdx.x;
    if (i < NN) count[i] = 0;
}

__global__ void k_hist(const int* __restrict__ dst, int* __restrict__ count) {
    int t = blockIdx.x * 256 + threadIdx.x;
    if (t < EDGES / 4) {
        int4 d = ((const int4*)dst)[t];
        atomicAdd(&count[d.x], 1);
        atomicAdd(&count[d.y], 1);
        atomicAdd(&count[d.z], 1);
        atomicAdd(&count[d.w], 1);
    }
}

__global__ __launch_bounds__(SCAN_BLK) void k_scanA(const int* __restrict__ count,
                                                    int* __restrict__ tmp,
                                                    int* __restrict__ blocksum) {
    __shared__ int s[SCAN_BLK];
    int i = blockIdx.x * SCAN_BLK + threadIdx.x;
    int v = (i < NN) ? count[i] : 0;
    s[threadIdx.x] = v;
    __syncthreads();
    for (int off = 1; off < SCAN_BLK; off <<= 1) {
        int t = (threadIdx.x >= off) ? s[threadIdx.x - off] : 0;
        __syncthreads();
        s[threadIdx.x] += t;
        __syncthreads();
    }
    if (i < NN) tmp[i] = s[threadIdx.x];
    if (threadIdx.x == SCAN_BLK - 1) blocksum[blockIdx.x] = s[SCAN_BLK - 1];
}

__global__ void k_scanB(const int* __restrict__ blocksum, int* __restrict__ blockoff, int nb) {
    __shared__ int s[128];
    int v = (threadIdx.x < nb) ? blocksum[threadIdx.x] : 0;
    s[threadIdx.x] = v;
    __syncthreads();
    for (int off = 1; off < 128; off <<= 1) {
        int t = (threadIdx.x >= off) ? s[threadIdx.x - off] : 0;
        __syncthreads();
        s[threadIdx.x] += t;
        __syncthreads();
    }
    if (threadIdx.x < nb) blockoff[threadIdx.x] = s[threadIdx.x] - v;  // exclusive
}

// row_ptr + coarse-bucket cursors (bucket start = exclusive prefix at node b*512)
__global__ void k_scanC(const int* __restrict__ tmp, const int* __restrict__ blockoff,
                        const int* __restrict__ count,
                        int* __restrict__ row_ptr, int* __restrict__ bcur) {
    int i = blockIdx.x * 256 + threadIdx.x;
    if (i < NN) {
        int incl = tmp[i] + blockoff[i / SCAN_BLK];
        row_ptr[i + 1] = incl;
        if (i == 0) row_ptr[0] = 0;
        if ((i & (BKT_W - 1)) == 0) bcur[i >> BKT_SH] = incl - count[i];
    }
}

// ---- Pass 1: single read of edges; LDS-bin by coarse bucket; one bulk
// reservation per bin; coalesced flush -> staging writes are ~full lines.
__global__ __launch_bounds__(256) void k_scat1(const int* __restrict__ src,
                                               const int* __restrict__ dst,
                                               const float* __restrict__ val,
                                               int* __restrict__ bcur,
                                               int2* __restrict__ staging) {
    __shared__ int2 bins[NBKT][CAP];      // 98*64*8 = 50 KB
    __shared__ int bincnt[NBKT];
    __shared__ int binbase[NBKT];
    const int tid = threadIdx.x;
    for (int b = tid; b < NBKT; b += 256) bincnt[b] = 0;
    __syncthreads();

    const int base = blockIdx.x * CHUNK1;
    const int end  = min(base + CHUNK1, EDGES);
    for (int e = base + tid; e < end; e += 256) {
        int d = dst[e];
        int b = d >> BKT_SH;
        int2 cv = make_int2(src[e] | ((d & (BKT_W - 1)) << 17), __float_as_int(val[e]));
        int slot = atomicAdd(&bincnt[b], 1);
        if (slot < CAP) {
            bins[b][slot] = cv;
        } else {                          // rare tail: direct append
            int p = atomicAdd(&bcur[b], 1);
            staging[p] = cv;
        }
    }
    __syncthreads();

    if (tid < NBKT) {                     // parallel bulk reservations
        int n = min(bincnt[tid], CAP);
        bincnt[tid]  = n;
        binbase[tid] = atomicAdd(&bcur[tid], n);
    }
    __syncthreads();

    const int wid = tid >> 6, lane = tid & 63;
    for (int b = wid; b < NBKT; b += 4) { // coalesced flush
        int n = bincnt[b], bb = binbase[b];
        for (int i = lane; i < n; i += 64)
            staging[bb + i] = bins[b][i];
    }
}

// ---- Pass 2: one block per coarse bucket; exact placement via LDS cursors;
// writes fully cover the block's own CSR window -> merged writebacks.
__global__ __launch_bounds__(256) void k_scat2(const int* __restrict__ row_ptr,
                                               const int2* __restrict__ staging,
                                               int2* __restrict__ csr) {
    __shared__ int cur[BKT_W];
    const int nb = blockIdx.x << BKT_SH;
    for (int t = threadIdx.x; t < BKT_W; t += 256) {
        int node = nb + t;
        cur[t] = (node < NN) ? row_ptr[node] : 0;
    }
    __syncthreads();
    const int beg = row_ptr[nb];
    const int end = row_ptr[min(nb + BKT_W, NN)];
    for (int i = beg + threadIdx.x; i < end; i += 256) {
        int2 cv = staging[i];
        int dl = cv.x >> 17;
        int p  = atomicAdd(&cur[dl], 1);
        csr[p] = make_int2(cv.x & 0x1FFFF, cv.y);
    }
}

// ---------------- SPMM: out[r,:] = sum_j val_j * in[col_j,:]  (d=64) --------
template <bool RELU>
__global__ __launch_bounds__(256) void k_spmm(const float* __restrict__ in,
                                              const int* __restrict__ row_ptr,
                                              const int2* __restrict__ csr,
                                              const float* __restrict__ bias,
                                              float* __restrict__ out) {
    const int lane = threadIdx.x & 63;
    int gw = (blockIdx.x * 256 + threadIdx.x) >> 6;
    if (gw >= NN) return;
    const int r   = __builtin_amdgcn_readfirstlane(gw);
    const int beg = row_ptr[r];
    const int end = row_ptr[r + 1];

    float acc0 = 0.f, acc1 = 0.f;
    int j = beg;
    for (; j + 3 < end; j += 4) {
        int2 a = csr[j], b = csr[j + 1], c = csr[j + 2], d = csr[j + 3];
        acc0 += __int_as_float(a.y) * in[(size_t)a.x * NHID + lane];
        acc1 += __int_as_float(b.y) * in[(size_t)b.x * NHID + lane];
        acc0 += __int_as_float(c.y) * in[(size_t)c.x * NHID + lane];
        acc1 += __int_as_float(d.y) * in[(size_t)d.x * NHID + lane];
    }
    for (; j < end; ++j) {
        int2 a = csr[j];
        acc0 += __int_as_float(a.y) * in[(size_t)a.x * NHID + lane];
    }
    float acc = acc0 + acc1;

    if (RELU)
        out[(size_t)r * NHID + lane] = fmaxf(acc + bias[lane], 0.f);
    else
        out[(size_t)r * NHID + lane] = acc;
}

// ---------------- Fused epilogue: heads + reparam + log_softmax -------------
__global__ __launch_bounds__(256) void k_final(const float* __restrict__ g2,
                                               const float* __restrict__ W11,
                                               const float* __restrict__ b11,
                                               const float* __restrict__ W12,
                                               const float* __restrict__ b12,
                                               const float* __restrict__ eps,
                                               float* __restrict__ out) {
    __shared__ float W11l[NHID * NCLASS];
    __shared__ float W12l[NHID * NCLASS];
    __shared__ float bl[2 * NCLASS];
    for (int i = threadIdx.x; i < NHID * NCLASS; i += 256) {
        W11l[i] = W11[i];
        W12l[i] = W12[i];
    }
    if (threadIdx.x < NCLASS) bl[threadIdx.x] = b11[threadIdx.x];
    else if (threadIdx.x < 2 * NCLASS) bl[threadIdx.x] = b12[threadIdx.x - NCLASS];
    __syncthreads();

    const int lane = threadIdx.x & 63;
    const int gw   = (blockIdx.x * 256 + threadIdx.x) >> 6;
    const bool act = lane < NCLASS;
    const int  cc  = act ? lane : NCLASS - 1;

    const int r0 = gw * 4;
    if (r0 >= NN) return;
    const int ur = __builtin_amdgcn_readfirstlane(r0);
    const float* __restrict__ g = g2 + (size_t)ur * NHID;

    float m[4], lg[4];
    #pragma unroll
    for (int i = 0; i < 4; ++i) { m[i] = bl[cc]; lg[i] = bl[NCLASS + cc]; }

    #pragma unroll 4
    for (int k = 0; k < NHID; ++k) {
        float w1 = W11l[k * NCLASS + cc];
        float w2 = W12l[k * NCLASS + cc];
        float ga = g[k], gb = g[NHID + k], gc = g[2 * NHID + k], gd = g[3 * NHID + k];
        m[0] += ga * w1; lg[0] += ga * w2;
        m[1] += gb * w1; lg[1] += gb * w2;
        m[2] += gc * w1; lg[2] += gc * w2;
        m[3] += gd * w1; lg[3] += gd * w2;
    }

    float z[4];
    #pragma unroll
    for (int i = 0; i < 4; ++i)
        z[i] = act ? (eps[(size_t)(ur + i) * NCLASS + lane] * expf(lg[i]) + m[i]) : -1e30f;

    float zmax[4], s[4];
    #pragma unroll
    for (int i = 0; i < 4; ++i) zmax[i] = z[i];
    #pragma unroll
    for (int off = 32; off >= 1; off >>= 1) {
        #pragma unroll
        for (int i = 0; i < 4; ++i) zmax[i] = fmaxf(zmax[i], __shfl_xor(zmax[i], off));
    }
    #pragma unroll
    for (int i = 0; i < 4; ++i) s[i] = act ? expf(z[i] - zmax[i]) : 0.f;
    #pragma unroll
    for (int off = 32; off >= 1; off >>= 1) {
        #pragma unroll
        for (int i = 0; i < 4; ++i) s[i] += __shfl_xor(s[i], off);
    }
    if (act) {
        #pragma unroll
        for (int i = 0; i < 4; ++i)
            out[(size_t)(ur + i) * NCLASS + lane] = z[i] - zmax[i] - logf(s[i]);
    }
}

// ---------------- launcher --------------------------------------------------
extern "C" void kernel_launch(void* const* d_in, const int* in_sizes, int n_in,
                              void* d_out, int out_size, void* d_ws, size_t ws_size,
                              hipStream_t stream) {
    const float* x        = (const float*)d_in[0];
    const int*   edge_src = (const int*)d_in[1];
    const int*   edge_dst = (const int*)d_in[2];
    const float* edge_val = (const float*)d_in[3];
    const float* eps      = (const float*)d_in[4];
    const float* W1       = (const float*)d_in[5];
    const float* b1       = (const float*)d_in[6];
    const float* W11      = (const float*)d_in[7];
    const float* b11      = (const float*)d_in[8];
    const float* W12      = (const float*)d_in[9];
    const float* b12      = (const float*)d_in[10];
    float* out = (float*)d_out;

    // ws layout; staging aliases h (h first written in spmm1, after scat2)
    int2*  csr     = (int2*)d_ws;                  // EDGES * 8B
    float* xw      = (float*)(csr + EDGES);        // NN*64
    float* h       = xw + (size_t)NN * NHID;       // NN*64
    int2*  staging = (int2*)h;                     // EDGES * 8B (alias)
    int*   count   = (int*)(h + (size_t)NN * NHID);
    int*   tmp     = count + NN;
    int*   row_ptr = tmp + NN;                     // NN+1
    int*   bcur    = row_ptr + (NN + 1);           // NBKT
    int*   blocksum= bcur + NBKT;
    int*   blockoff= blocksum + 128;
    float* g2 = xw;                                // xw dead after spmm1

    const int NB = (NN + SCAN_BLK - 1) / SCAN_BLK; // 98

    k_gemm1<<<(NN + BM - 1) / BM, 256, 0, stream>>>(x, W1, xw);
    k_zero<<<(NN + 255) / 256, 256, 0, stream>>>(count);
    k_hist<<<(EDGES / 4 + 255) / 256, 256, 0, stream>>>(edge_dst, count);
    k_scanA<<<NB, SCAN_BLK, 0, stream>>>(count, tmp, blocksum);
    k_scanB<<<1, 128, 0, stream>>>(blocksum, blockoff, NB);
    k_scanC<<<(NN + 255) / 256, 256, 0, stream>>>(tmp, blockoff, count, row_ptr, bcur);
    k_scat1<<<NBLK1, 256, 0, stream>>>(edge_src, edge_dst, edge_val, bcur, staging);
    k_scat2<<<NBKT, 256, 0, stream>>>(row_ptr, staging, csr);
    k_spmm<true><<<NN / 4, 256, 0, stream>>>(xw, row_ptr, csr, b1, h);
    k_spmm<false><<<NN / 4, 256, 0, stream>>>(h, row_ptr, csr, nullptr, g2);
    k_final<<<(NN / 4 + 3) / 4, 256, 0, stream>>>(g2, W11, b11, W12, b12, eps, out);
}